// Round 6
// baseline (155.455 us; speedup 1.0000x reference)
//
#include <hip/hip_runtime.h>
#include <hip/hip_bf16.h>

using bf16 = __hip_bfloat16;
typedef __attribute__((ext_vector_type(8))) short frag_ab;   // 8 bf16
typedef __attribute__((ext_vector_type(4))) float frag_cd;   // 4 fp32

constexpr float TEMP   = 0.07f;
constexpr float INVT   = 1.0f / TEMP;                 // fixed logsumexp shift
constexpr float THRESH = 0.1f;
constexpr float EPS    = 1e-8f;
constexpr float LOG2E  = 1.4426950408889634f;
constexpr float C1     = LOG2E / TEMP;                // exp((s-1)/T) = exp2(s*C1 - C1)

constexpr int D  = 128;
constexpr int TC = 128;   // tile size (rows and cols): block (R,C) does a 128x128 tile

__device__ __forceinline__ frag_cd mfma16(frag_ab a, frag_ab b, frag_cd c) {
    return __builtin_amdgcn_mfma_f32_16x16x32_bf16(a, b, c, 0, 0, 0);
}

// async global->LDS DMA, 16B per lane, LDS dest = wave-uniform base + lane*16
__device__ __forceinline__ void async_copy16(const bf16* gp, bf16* lp) {
    __builtin_amdgcn_global_load_lds(
        (__attribute__((address_space(1))) void*)(gp),
        (__attribute__((address_space(3))) void*)(lp), 16, 0, 0);
}

// ------- kernel 1: row-normalize -> bf16, diagonal dot, zero global accumulators -------
__global__ __launch_bounds__(256) void k1_normalize(
    const float* __restrict__ f, bf16* __restrict__ fn,
    float* __restrict__ diag, float* __restrict__ se_g,
    float* __restrict__ sp_g, float* __restrict__ cnt_g,
    float* __restrict__ acc, unsigned* __restrict__ counter, int n)
{
    if (blockIdx.x == 0 && threadIdx.x == 0) { acc[0] = 0.f; counter[0] = 0u; }
    // zero the atomically-accumulated per-row arrays (first 32 blocks cover n=8192)
    const int gid = blockIdx.x * 256 + threadIdx.x;
    if (gid < n) { se_g[gid] = 0.f; sp_g[gid] = 0.f; cnt_g[gid] = 0.f; }

    const int row  = blockIdx.x * 4 + (threadIdx.x >> 6);
    const int lane = threadIdx.x & 63;
    float2 v = ((const float2*)(f + (size_t)row * D))[lane];
    float ss = v.x * v.x + v.y * v.y;
    #pragma unroll
    for (int m = 32; m >= 1; m >>= 1) ss += __shfl_xor(ss, m, 64);
    const float inv = 1.0f / fmaxf(sqrtf(ss), EPS);
    __hip_bfloat162 o;
    o.x = __float2bfloat16(v.x * inv);
    o.y = __float2bfloat16(v.y * inv);
    ((__hip_bfloat162*)(fn + (size_t)row * D))[lane] = o;
    // diagonal raw dot of the bf16-rounded row (matches MFMA s_ii to ~1e-6)
    const float a = __bfloat162float(o.x), b = __bfloat162float(o.y);
    float p = a * a + b * b;
    #pragma unroll
    for (int m = 32; m >= 1; m >>= 1) p += __shfl_xor(p, m, 64);
    if (lane == 0) diag[row] = p;
}

// ---------------- kernel 2: SYMMETRIC fused sim + masked reductions ----------------
// sim(i,j)==sim(j,i): grid (64,64), block (R,C) live iff C>=R -> 2080 live tiles vs
// 4096 tile-equivalents before (1.97x less MFMA+exp2+epilogue VALU). Each live block
// computes its 128x128 tile ONCE and credits BOTH endpoints:
//   row-side: 16-lane reduce (as before) -> atomicAdd to rows in R
//   col-side: quad reduce (shfl_xor 16,32) -> per-wave LDS stage -> atomicAdd to rows in C
// Diagonal blocks (R==C) credit row-side only (full tile covers all (i,j) in-block).
// Single col-tile DMA (R3/R5-verified m173 pre-swizzled-source pattern), TWO barriers
// per block total (vs 9 before).
// LAUNCH-BOUNDS LAW (R0/R2/R4): arch-VGPR cap = 256/min_waves; (256,3)->85 is the
// proven-safe bound for this ~75-reg kernel. DO NOT RAISE min_waves.
__global__ __launch_bounds__(256, 3) void k2_main(
    const bf16* __restrict__ fn, const float* __restrict__ lab,
    float* __restrict__ se_g, float* __restrict__ sp_g,
    float* __restrict__ cnt_g, int n)
{
    const int Rb = blockIdx.x, Cb = blockIdx.y;
    if (Cb < Rb) return;                      // dead half of the grid retires instantly
    const bool diagblk = (Cb == Rb);

    __shared__ bf16  colbuf[TC * D];          // 32 KB, swizzled: col c slot s holds chunk s^(c&15)
    __shared__ float lab_s[TC];
    __shared__ float csum[4][3][TC];          // per-wave col partials (off-diag only), 6 KB

    const int tid  = threadIdx.x;
    const int wave = tid >> 6;
    const int lane = tid & 63;
    const int quad = lane >> 4;
    const int l15  = lane & 15;

    const int row_base = Rb * TC + wave * 32;
    const int col_base = Cb * TC;

    if (tid < TC) lab_s[tid] = lab[col_base + tid];

    // DMA the col tile: 8 issues/wave, issue i lane l -> LDS byte wave*8192+i*1024+l*16
    //   col ci = wave*32 + i*4 + (l>>4), slot l&15, source chunk = l15 ^ (ci&15)
    {
        const bf16* gt = fn + (size_t)col_base * D;
        bf16* lb = &colbuf[wave * 4096];
        #pragma unroll
        for (int i = 0; i < 8; ++i) {
            const int ci = wave * 32 + i * 4 + (lane >> 4);
            const int ki = l15 ^ (ci & 15);
            async_copy16(gt + (size_t)ci * D + ki * 8, lb + i * 512);
        }
    }

    // A fragments (overlap the DMA): set s covers rows row_base+s*16+l15, k=kb*32+quad*8+j
    frag_ab afr[2][4];
    #pragma unroll
    for (int s = 0; s < 2; ++s) {
        const bf16* ap = fn + (size_t)(row_base + s * 16 + l15) * D + quad * 8;
        #pragma unroll
        for (int kb = 0; kb < 4; ++kb) afr[s][kb] = *(const frag_ab*)(ap + kb * 32);
    }
    float li[2][4];
    #pragma unroll
    for (int s = 0; s < 2; ++s)
        #pragma unroll
        for (int r = 0; r < 4; ++r)
            li[s][r] = lab[row_base + s * 16 + quad * 4 + r];

    float se[2][4] = {}, sp[2][4] = {}, cnt[2][4] = {};

    __syncthreads();   // drains DMA vmcnt; colbuf + lab_s ready

    #pragma unroll
    for (int sub = 0; sub < 8; ++sub) {
        const int c = sub * 16 + l15;          // column within tile (c&15 == l15)
        frag_ab b[4];
        #pragma unroll
        for (int kb = 0; kb < 4; ++kb)
            b[kb] = *(const frag_ab*)(&colbuf[(size_t)c * D + (((quad + 4 * kb) ^ l15) * 8)]);
        frag_cd a0 = {0.f, 0.f, 0.f, 0.f}, a1 = {0.f, 0.f, 0.f, 0.f};
        #pragma unroll
        for (int kb = 0; kb < 4; ++kb) {
            a0 = mfma16(afr[0][kb], b[kb], a0);
            a1 = mfma16(afr[1][kb], b[kb], a1);
        }
        const float lj = lab_s[c];
        float cs_e = 0.f, cs_sp = 0.f, cs_cnt = 0.f;
        #pragma unroll
        for (int s = 0; s < 2; ++s) {
            const frag_cd& acc = s ? a1 : a0;
            #pragma unroll
            for (int r = 0; r < 4; ++r) {
                const float sv = acc[r];                      // raw dot (cosine)
                const float e  = __builtin_amdgcn_exp2f(__builtin_fmaf(sv, C1, -C1));
                const float pm = (fabsf(li[s][r] - lj) < THRESH) ? 1.0f : 0.0f;
                se[s][r]  += e;
                sp[s][r]   = __builtin_fmaf(pm, sv, sp[s][r]); // raw dots; 1/T in k3
                cnt[s][r] += pm;
                cs_e  += e;                                    // col-side (symmetric credit)
                cs_sp  = __builtin_fmaf(pm, sv, cs_sp);
                cs_cnt += pm;
            }
        }
        if (!diagblk) {
            // reduce over the 4 quads -> col totals for this wave's 32 rows
            cs_e  += __shfl_xor(cs_e, 16, 64);  cs_e  += __shfl_xor(cs_e, 32, 64);
            cs_sp += __shfl_xor(cs_sp, 16, 64); cs_sp += __shfl_xor(cs_sp, 32, 64);
            cs_cnt+= __shfl_xor(cs_cnt,16, 64); cs_cnt+= __shfl_xor(cs_cnt,32, 64);
            if (lane < 16) {
                csum[wave][0][c] = cs_e;
                csum[wave][1][c] = cs_sp;
                csum[wave][2][c] = cs_cnt;
            }
        }
    }

    // row-side: reduce across the 16 lanes of each quad-group, then global atomics
    #pragma unroll
    for (int s = 0; s < 2; ++s)
        #pragma unroll
        for (int r = 0; r < 4; ++r) {
            #pragma unroll
            for (int m = 1; m < 16; m <<= 1) {
                se[s][r]  += __shfl_xor(se[s][r],  m, 64);
                sp[s][r]  += __shfl_xor(sp[s][r],  m, 64);
                cnt[s][r] += __shfl_xor(cnt[s][r], m, 64);
            }
        }
    if (l15 == 0) {
        #pragma unroll
        for (int s = 0; s < 2; ++s)
            #pragma unroll
            for (int r = 0; r < 4; ++r) {
                const int i = row_base + s * 16 + quad * 4 + r;
                atomicAdd(&se_g[i],  se[s][r]);
                atomicAdd(&sp_g[i],  sp[s][r]);
                atomicAdd(&cnt_g[i], cnt[s][r]);
            }
    }

    // col-side combine (off-diag only; block-uniform branch so the barrier is safe)
    if (!diagblk) {
        __syncthreads();                       // csum ds_writes visible
        if (tid < TC) {
            const float ve = csum[0][0][tid] + csum[1][0][tid] + csum[2][0][tid] + csum[3][0][tid];
            const float vs = csum[0][1][tid] + csum[1][1][tid] + csum[2][1][tid] + csum[3][1][tid];
            const float vc = csum[0][2][tid] + csum[1][2][tid] + csum[2][2][tid] + csum[3][2][tid];
            atomicAdd(&se_g[col_base + tid],  ve);
            atomicAdd(&sp_g[col_base + tid],  vs);
            atomicAdd(&cnt_g[col_base + tid], vc);
        }
    }
}

// ------- kernel 3: per-row finalize + grid reduction (last-block pattern) -------
__global__ __launch_bounds__(256) void k3_finalize(
    const float* __restrict__ diag, const float* __restrict__ se_g,
    const float* __restrict__ sp_g, const float* __restrict__ cnt_g,
    float* __restrict__ acc, unsigned* __restrict__ counter,
    float* __restrict__ out, int n)
{
    const int row = blockIdx.x * 256 + threadIdx.x;
    float se  = se_g[row];
    float sp  = sp_g[row];
    float cnt = cnt_g[row];
    const float s_ii = diag[row];
    se  -= __builtin_amdgcn_exp2f(__builtin_fmaf(s_ii, C1, -C1));
    sp  -= s_ii;
    cnt -= 1.0f;
    float loss = INVT + __logf(se) - (sp * INVT) / fmaxf(cnt, 1.0f);

    // block reduce
    #pragma unroll
    for (int m = 32; m >= 1; m >>= 1) loss += __shfl_xor(loss, m, 64);
    __shared__ float wsum[4];
    if ((threadIdx.x & 63) == 0) wsum[threadIdx.x >> 6] = loss;
    __syncthreads();
    if (threadIdx.x == 0) {
        const float bs = wsum[0] + wsum[1] + wsum[2] + wsum[3];
        atomicAdd(acc, bs);
        __threadfence();
        const unsigned old = atomicAdd(counter, 1u);
        if (old == gridDim.x - 1) {
            const float total = atomicAdd(acc, 0.0f);  // atomic load, same-address order
            out[0] = total / (float)n;
        }
    }
}

extern "C" void kernel_launch(void* const* d_in, const int* in_sizes, int n_in,
                              void* d_out, int out_size, void* d_ws, size_t ws_size,
                              hipStream_t stream) {
    const float* feat = (const float*)d_in[0];
    const float* lab  = (const float*)d_in[1];
    const int n = in_sizes[1];              // 8192
    float* out = (float*)d_out;

    // ws: fn (n*D bf16 = 2MB) | diag | se_g | sp_g | cnt_g (each n f32) | acc | counter
    char* ws = (char*)d_ws;
    bf16* fn = (bf16*)ws;
    size_t off = (size_t)n * D * sizeof(bf16);
    float* diag  = (float*)(ws + off); off += (size_t)n * sizeof(float);
    float* se_g  = (float*)(ws + off); off += (size_t)n * sizeof(float);
    float* sp_g  = (float*)(ws + off); off += (size_t)n * sizeof(float);
    float* cnt_g = (float*)(ws + off); off += (size_t)n * sizeof(float);
    float* acc   = (float*)(ws + off); off += sizeof(float);
    unsigned* counter = (unsigned*)(ws + off);

    k1_normalize<<<n / 4, 256, 0, stream>>>(feat, fn, diag, se_g, sp_g, cnt_g, acc, counter, n);
    dim3 g2(n / TC, n / TC);                // (64,64); blocks with Cb<Rb exit immediately
    k2_main<<<g2, 256, 0, stream>>>(fn, lab, se_g, sp_g, cnt_g, n);
    k3_finalize<<<n / 256, 256, 0, stream>>>(diag, se_g, sp_g, cnt_g, acc, counter, out, n);
}

// Round 7
// 153.040 us; speedup vs baseline: 1.0158x; 1.0158x over previous
//
#include <hip/hip_runtime.h>
#include <hip/hip_bf16.h>

using bf16 = __hip_bfloat16;
typedef __attribute__((ext_vector_type(8))) short frag_ab;   // 8 bf16
typedef __attribute__((ext_vector_type(4))) float frag_cd;   // 4 fp32

constexpr float TEMP   = 0.07f;
constexpr float INVT   = 1.0f / TEMP;                 // fixed logsumexp shift
constexpr float THRESH = 0.1f;
constexpr float EPS    = 1e-8f;
constexpr float LOG2E  = 1.4426950408889634f;
constexpr float C1     = LOG2E / TEMP;                // exp((s-1)/T) = exp2(s*C1 - C1)

constexpr int D  = 128;
constexpr int TC = 128;   // tile size (rows and cols): block (R,C) does a 128x128 tile

__device__ __forceinline__ frag_cd mfma16(frag_ab a, frag_ab b, frag_cd c) {
    return __builtin_amdgcn_mfma_f32_16x16x32_bf16(a, b, c, 0, 0, 0);
}

// async global->LDS DMA, 16B per lane, LDS dest = wave-uniform base + lane*16
__device__ __forceinline__ void async_copy16(const bf16* gp, bf16* lp) {
    __builtin_amdgcn_global_load_lds(
        (__attribute__((address_space(1))) void*)(gp),
        (__attribute__((address_space(3))) void*)(lp), 16, 0, 0);
}

// ------- kernel 1: row-normalize -> bf16, diagonal dot, zero-init acc/counter -------
__global__ __launch_bounds__(256) void k1_normalize(
    const float* __restrict__ f, bf16* __restrict__ fn,
    float* __restrict__ diag, float* __restrict__ acc,
    unsigned* __restrict__ counter, int n)
{
    if (blockIdx.x == 0 && threadIdx.x == 0) { acc[0] = 0.f; counter[0] = 0u; }
    const int row  = blockIdx.x * 4 + (threadIdx.x >> 6);
    const int lane = threadIdx.x & 63;
    float2 v = ((const float2*)(f + (size_t)row * D))[lane];
    float ss = v.x * v.x + v.y * v.y;
    #pragma unroll
    for (int m = 32; m >= 1; m >>= 1) ss += __shfl_xor(ss, m, 64);
    const float inv = 1.0f / fmaxf(sqrtf(ss), EPS);
    __hip_bfloat162 o;
    o.x = __float2bfloat16(v.x * inv);
    o.y = __float2bfloat16(v.y * inv);
    ((__hip_bfloat162*)(fn + (size_t)row * D))[lane] = o;
    // diagonal raw dot of the bf16-rounded row (matches MFMA s_ii to ~1e-6)
    const float a = __bfloat162float(o.x), b = __bfloat162float(o.y);
    float p = a * a + b * b;
    #pragma unroll
    for (int m = 32; m >= 1; m >>= 1) p += __shfl_xor(p, m, 64);
    if (lane == 0) diag[row] = p;
}

// ---------------- kernel 2: SYMMETRIC fused sim + masked reductions, NO ATOMICS ----------------
// sim(i,j)==sim(j,i): only the upper triangle of 128x128 tiles is computed (2080 blocks,
// linearized). Block (R,C), C>=R, credits BOTH endpoints via disjoint PARTIAL-SPLIT slots:
//   row-side -> split C, rows in R   (plain stores, one writer per (split,row))
//   col-side -> split R, rows in C   (off-diag only; diag blocks cover their rows fully)
// For row i in block-row Rb: splits s>=Rb come from block (Rb,s) row-side, s<Rb from
// block (s,Rb) col-side => every (split,row) cell written exactly once; k3 sums 64 splits.
// R6 post-mortem: the previous symmetric version used device-scope atomicAdd for credit
// delivery -> 1.6M cross-XCD fabric RMWs (WRITE_SIZE 142 MB) -> k2 103us. Splits fix that.
// LAUNCH-BOUNDS LAW (R0/R2/R4): arch-VGPR cap = 256/min_waves; (256,3)->85 proven safe.
__global__ __launch_bounds__(256, 3) void k2_main(
    const bf16* __restrict__ fn, const float* __restrict__ lab,
    float* __restrict__ se_p, float* __restrict__ sp_p,
    float* __restrict__ cnt_p, int n, int nb)
{
    // linear triangle decode: bid -> (Rb, Cb), 0 <= Rb <= Cb < nb
    // Offset(R) = R*(2*nb - R + 1)/2 tiles precede block-row R
    const int bid = blockIdx.x;
    int Rb = (int)floorf(((2.0f * nb + 1.0f)
              - sqrtf((2.0f * nb + 1.0f) * (2.0f * nb + 1.0f) - 8.0f * (float)bid)) * 0.5f);
    while ((Rb + 1) * (2 * nb - Rb) / 2 <= bid) ++Rb;       // f32 decode correction
    while (Rb * (2 * nb - Rb + 1) / 2 > bid) --Rb;
    const int Cb = Rb + (bid - Rb * (2 * nb - Rb + 1) / 2);
    const bool diagblk = (Cb == Rb);

    __shared__ bf16  colbuf[TC * D];          // 32 KB, swizzled: col c slot s holds chunk s^(c&15)
    __shared__ float lab_s[TC];
    __shared__ float csum[4][3][TC];          // per-wave col partials (off-diag only), 6 KB

    const int tid  = threadIdx.x;
    const int wave = tid >> 6;
    const int lane = tid & 63;
    const int quad = lane >> 4;
    const int l15  = lane & 15;

    const int row_base = Rb * TC + wave * 32;
    const int col_base = Cb * TC;

    if (tid < TC) lab_s[tid] = lab[col_base + tid];

    // DMA the col tile: 8 issues/wave, issue i lane l -> LDS byte wave*8192+i*1024+l*16
    //   col ci = wave*32 + i*4 + (l>>4), slot l&15, source chunk = l15 ^ (ci&15)
    {
        const bf16* gt = fn + (size_t)col_base * D;
        bf16* lb = &colbuf[wave * 4096];
        #pragma unroll
        for (int i = 0; i < 8; ++i) {
            const int ci = wave * 32 + i * 4 + (lane >> 4);
            const int ki = l15 ^ (ci & 15);
            async_copy16(gt + (size_t)ci * D + ki * 8, lb + i * 512);
        }
    }

    // A fragments (overlap the DMA): set s covers rows row_base+s*16+l15, k=kb*32+quad*8+j
    frag_ab afr[2][4];
    #pragma unroll
    for (int s = 0; s < 2; ++s) {
        const bf16* ap = fn + (size_t)(row_base + s * 16 + l15) * D + quad * 8;
        #pragma unroll
        for (int kb = 0; kb < 4; ++kb) afr[s][kb] = *(const frag_ab*)(ap + kb * 32);
    }
    float li[2][4];
    #pragma unroll
    for (int s = 0; s < 2; ++s)
        #pragma unroll
        for (int r = 0; r < 4; ++r)
            li[s][r] = lab[row_base + s * 16 + quad * 4 + r];

    float se[2][4] = {}, sp[2][4] = {}, cnt[2][4] = {};

    __syncthreads();   // drains DMA vmcnt; colbuf + lab_s ready

    #pragma unroll
    for (int sub = 0; sub < 8; ++sub) {
        const int c = sub * 16 + l15;          // column within tile (c&15 == l15)
        frag_ab b[4];
        #pragma unroll
        for (int kb = 0; kb < 4; ++kb)
            b[kb] = *(const frag_ab*)(&colbuf[(size_t)c * D + (((quad + 4 * kb) ^ l15) * 8)]);
        frag_cd a0 = {0.f, 0.f, 0.f, 0.f}, a1 = {0.f, 0.f, 0.f, 0.f};
        #pragma unroll
        for (int kb = 0; kb < 4; ++kb) {
            a0 = mfma16(afr[0][kb], b[kb], a0);
            a1 = mfma16(afr[1][kb], b[kb], a1);
        }
        const float lj = lab_s[c];
        float cs_e = 0.f, cs_sp = 0.f, cs_cnt = 0.f;
        #pragma unroll
        for (int s = 0; s < 2; ++s) {
            const frag_cd& acc = s ? a1 : a0;
            #pragma unroll
            for (int r = 0; r < 4; ++r) {
                const float sv = acc[r];                      // raw dot (cosine)
                const float e  = __builtin_amdgcn_exp2f(__builtin_fmaf(sv, C1, -C1));
                const float pm = (fabsf(li[s][r] - lj) < THRESH) ? 1.0f : 0.0f;
                se[s][r]  += e;
                sp[s][r]   = __builtin_fmaf(pm, sv, sp[s][r]); // raw dots; 1/T in k3
                cnt[s][r] += pm;
                cs_e  += e;                                    // col-side (symmetric credit)
                cs_sp  = __builtin_fmaf(pm, sv, cs_sp);
                cs_cnt += pm;
            }
        }
        if (!diagblk) {
            // reduce over the 4 quads -> col totals for this wave's 32 rows
            cs_e  += __shfl_xor(cs_e, 16, 64);  cs_e  += __shfl_xor(cs_e, 32, 64);
            cs_sp += __shfl_xor(cs_sp, 16, 64); cs_sp += __shfl_xor(cs_sp, 32, 64);
            cs_cnt+= __shfl_xor(cs_cnt,16, 64); cs_cnt+= __shfl_xor(cs_cnt,32, 64);
            if (lane < 16) {
                csum[wave][0][c] = cs_e;
                csum[wave][1][c] = cs_sp;
                csum[wave][2][c] = cs_cnt;
            }
        }
    }

    // row-side: reduce across the 16 lanes of each quad-group -> split Cb (plain stores)
    #pragma unroll
    for (int s = 0; s < 2; ++s)
        #pragma unroll
        for (int r = 0; r < 4; ++r) {
            #pragma unroll
            for (int m = 1; m < 16; m <<= 1) {
                se[s][r]  += __shfl_xor(se[s][r],  m, 64);
                sp[s][r]  += __shfl_xor(sp[s][r],  m, 64);
                cnt[s][r] += __shfl_xor(cnt[s][r], m, 64);
            }
        }
    if (l15 == 0) {
        #pragma unroll
        for (int s = 0; s < 2; ++s)
            #pragma unroll
            for (int r = 0; r < 4; ++r) {
                const int i = row_base + s * 16 + quad * 4 + r;
                se_p[(size_t)Cb * n + i]  = se[s][r];
                sp_p[(size_t)Cb * n + i]  = sp[s][r];
                cnt_p[(size_t)Cb * n + i] = cnt[s][r];
            }
    }

    // col-side combine -> split Rb (off-diag only; block-uniform branch, barrier safe)
    if (!diagblk) {
        __syncthreads();                       // csum ds_writes visible
        if (tid < TC) {
            const float ve = csum[0][0][tid] + csum[1][0][tid] + csum[2][0][tid] + csum[3][0][tid];
            const float vs = csum[0][1][tid] + csum[1][1][tid] + csum[2][1][tid] + csum[3][1][tid];
            const float vc = csum[0][2][tid] + csum[1][2][tid] + csum[2][2][tid] + csum[3][2][tid];
            se_p[(size_t)Rb * n + col_base + tid]  = ve;
            sp_p[(size_t)Rb * n + col_base + tid]  = vs;
            cnt_p[(size_t)Rb * n + col_base + tid] = vc;
        }
    }
}

// ------- kernel 3: per-row finalize (sum 64 splits) + grid reduction (last-block) -------
__global__ __launch_bounds__(256) void k3_finalize(
    const float* __restrict__ diag, const float* __restrict__ se_p,
    const float* __restrict__ sp_p, const float* __restrict__ cnt_p,
    float* __restrict__ acc, unsigned* __restrict__ counter,
    float* __restrict__ out, int n, int nb)
{
    const int row = blockIdx.x * 256 + threadIdx.x;
    float se = 0.f, sp = 0.f, cnt = 0.f;
    for (int s = 0; s < nb; ++s) {
        se  += se_p[(size_t)s * n + row];
        sp  += sp_p[(size_t)s * n + row];
        cnt += cnt_p[(size_t)s * n + row];
    }
    const float s_ii = diag[row];
    se  -= __builtin_amdgcn_exp2f(__builtin_fmaf(s_ii, C1, -C1));
    sp  -= s_ii;
    cnt -= 1.0f;
    float loss = INVT + __logf(se) - (sp * INVT) / fmaxf(cnt, 1.0f);

    // block reduce
    #pragma unroll
    for (int m = 32; m >= 1; m >>= 1) loss += __shfl_xor(loss, m, 64);
    __shared__ float wsum[4];
    if ((threadIdx.x & 63) == 0) wsum[threadIdx.x >> 6] = loss;
    __syncthreads();
    if (threadIdx.x == 0) {
        const float bs = wsum[0] + wsum[1] + wsum[2] + wsum[3];
        atomicAdd(acc, bs);
        __threadfence();
        const unsigned old = atomicAdd(counter, 1u);
        if (old == gridDim.x - 1) {
            const float total = atomicAdd(acc, 0.0f);  // atomic load, same-address order
            out[0] = total / (float)n;
        }
    }
}

extern "C" void kernel_launch(void* const* d_in, const int* in_sizes, int n_in,
                              void* d_out, int out_size, void* d_ws, size_t ws_size,
                              hipStream_t stream) {
    const float* feat = (const float*)d_in[0];
    const float* lab  = (const float*)d_in[1];
    const int n = in_sizes[1];              // 8192
    const int nb = n / TC;                  // 64 block-rows
    float* out = (float*)d_out;

    // ws: fn (n*D bf16 = 2MB) | diag (n f32) | se_p | sp_p | cnt_p (each nb*n f32 = 2MB)
    //     | acc | counter
    char* ws = (char*)d_ws;
    bf16* fn = (bf16*)ws;
    size_t off = (size_t)n * D * sizeof(bf16);
    float* diag  = (float*)(ws + off); off += (size_t)n * sizeof(float);
    float* se_p  = (float*)(ws + off); off += (size_t)nb * n * sizeof(float);
    float* sp_p  = (float*)(ws + off); off += (size_t)nb * n * sizeof(float);
    float* cnt_p = (float*)(ws + off); off += (size_t)nb * n * sizeof(float);
    float* acc   = (float*)(ws + off); off += sizeof(float);
    unsigned* counter = (unsigned*)(ws + off);

    k1_normalize<<<n / 4, 256, 0, stream>>>(feat, fn, diag, acc, counter, n);
    const int ntri = nb * (nb + 1) / 2;     // 2080 live tiles
    k2_main<<<ntri, 256, 0, stream>>>(fn, lab, se_p, sp_p, cnt_p, n, nb);
    k3_finalize<<<n / 256, 256, 0, stream>>>(diag, se_p, sp_p, cnt_p, acc, counter, out, n, nb);
}

// Round 8
// 120.009 us; speedup vs baseline: 1.2954x; 1.2752x over previous
//
#include <hip/hip_runtime.h>
#include <hip/hip_bf16.h>

using bf16 = __hip_bfloat16;
typedef __attribute__((ext_vector_type(8))) short frag_ab;   // 8 bf16
typedef __attribute__((ext_vector_type(4))) float frag_cd;   // 4 fp32

constexpr float TEMP   = 0.07f;
constexpr float INVT   = 1.0f / TEMP;                 // fixed logsumexp shift
constexpr float THRESH = 0.1f;
constexpr float EPS    = 1e-8f;
constexpr float LOG2E  = 1.4426950408889634f;
constexpr float C1     = LOG2E / TEMP;                // exp((s-1)/T) = exp2(s*C1 - C1)

constexpr int D  = 128;
constexpr int TC = 128;   // tile size (rows and cols): block (R,C) does a 128x128 tile

__device__ __forceinline__ frag_cd mfma16(frag_ab a, frag_ab b, frag_cd c) {
    return __builtin_amdgcn_mfma_f32_16x16x32_bf16(a, b, c, 0, 0, 0);
}

// async global->LDS DMA, 16B per lane, LDS dest = wave-uniform base + lane*16
__device__ __forceinline__ void async_copy16(const bf16* gp, bf16* lp) {
    __builtin_amdgcn_global_load_lds(
        (__attribute__((address_space(1))) void*)(gp),
        (__attribute__((address_space(3))) void*)(lp), 16, 0, 0);
}

// ------- kernel 1: row-normalize -> bf16, diagonal dot, zero-init acc/counter -------
__global__ __launch_bounds__(256) void k1_normalize(
    const float* __restrict__ f, bf16* __restrict__ fn,
    float* __restrict__ diag, float* __restrict__ acc,
    unsigned* __restrict__ counter, int n)
{
    if (blockIdx.x == 0 && threadIdx.x == 0) { acc[0] = 0.f; counter[0] = 0u; }
    const int row  = blockIdx.x * 4 + (threadIdx.x >> 6);
    const int lane = threadIdx.x & 63;
    float2 v = ((const float2*)(f + (size_t)row * D))[lane];
    float ss = v.x * v.x + v.y * v.y;
    #pragma unroll
    for (int m = 32; m >= 1; m >>= 1) ss += __shfl_xor(ss, m, 64);
    const float inv = 1.0f / fmaxf(sqrtf(ss), EPS);
    __hip_bfloat162 o;
    o.x = __float2bfloat16(v.x * inv);
    o.y = __float2bfloat16(v.y * inv);
    ((__hip_bfloat162*)(fn + (size_t)row * D))[lane] = o;
    // diagonal raw dot of the bf16-rounded row (matches MFMA s_ii to ~1e-6)
    const float a = __bfloat162float(o.x), b = __bfloat162float(o.y);
    float p = a * a + b * b;
    #pragma unroll
    for (int m = 32; m >= 1; m >>= 1) p += __shfl_xor(p, m, 64);
    if (lane == 0) diag[row] = p;
}

// ---------------- kernel 2: SYMMETRIC fused sim + masked reductions, NO ATOMICS ----------------
// sim(i,j)==sim(j,i): only the upper triangle of 128x128 tiles is computed (2080 blocks,
// linearized). Block (R,C), C>=R, credits BOTH endpoints via disjoint PARTIAL-SPLIT slots:
//   row-side -> split C, rows in R   (plain stores, one writer per (split,row))
//   col-side -> split R, rows in C   (off-diag only; diag blocks cover their rows fully)
// For row i in block-row Rb: splits s>=Rb come from block (Rb,s) row-side, s<Rb from
// block (s,Rb) col-side => every (split,row) cell written exactly once; k3 sums 64 splits.
//
// R7 post-mortem: at (256,3) [85-reg cap] this kernel's ~100-reg live state SPILLED
// (VGPR pinned at 84, ~120 MB scratch write + ~73 MB scratch read per dispatch — the
// "atomic traffic" of R6 was mostly this same spill). LAUNCH-BOUNDS LAW: cap=256/min_waves.
// (256,2) -> 128-reg cap fits ~100 live regs; NO occupancy loss because LDS (38.9 KB ->
// 4 blocks/CU = 4 waves/SIMD) binds first and <=128 VGPR also permits 4 waves/SIMD (m69).
__global__ __launch_bounds__(256, 2) void k2_main(
    const bf16* __restrict__ fn, const float* __restrict__ lab,
    float* __restrict__ se_p, float* __restrict__ sp_p,
    float* __restrict__ cnt_p, int n, int nb)
{
    // linear triangle decode: bid -> (Rb, Cb), 0 <= Rb <= Cb < nb
    // Offset(R) = R*(2*nb - R + 1)/2 tiles precede block-row R
    const int bid = blockIdx.x;
    int Rb = (int)floorf(((2.0f * nb + 1.0f)
              - sqrtf((2.0f * nb + 1.0f) * (2.0f * nb + 1.0f) - 8.0f * (float)bid)) * 0.5f);
    while ((Rb + 1) * (2 * nb - Rb) / 2 <= bid) ++Rb;       // f32 decode correction
    while (Rb * (2 * nb - Rb + 1) / 2 > bid) --Rb;
    const int Cb = Rb + (bid - Rb * (2 * nb - Rb + 1) / 2);
    const bool diagblk = (Cb == Rb);

    __shared__ bf16  colbuf[TC * D];          // 32 KB, swizzled: col c slot s holds chunk s^(c&15)
    __shared__ float lab_s[TC];
    __shared__ float csum[4][3][TC];          // per-wave col partials (off-diag only), 6 KB

    const int tid  = threadIdx.x;
    const int wave = tid >> 6;
    const int lane = tid & 63;
    const int quad = lane >> 4;
    const int l15  = lane & 15;

    const int row_base = Rb * TC + wave * 32;
    const int col_base = Cb * TC;

    if (tid < TC) lab_s[tid] = lab[col_base + tid];

    // DMA the col tile: 8 issues/wave, issue i lane l -> LDS byte wave*8192+i*1024+l*16
    //   col ci = wave*32 + i*4 + (l>>4), slot l&15, source chunk = l15 ^ (ci&15)
    {
        const bf16* gt = fn + (size_t)col_base * D;
        bf16* lb = &colbuf[wave * 4096];
        #pragma unroll
        for (int i = 0; i < 8; ++i) {
            const int ci = wave * 32 + i * 4 + (lane >> 4);
            const int ki = l15 ^ (ci & 15);
            async_copy16(gt + (size_t)ci * D + ki * 8, lb + i * 512);
        }
    }

    // A fragments (overlap the DMA): set s covers rows row_base+s*16+l15, k=kb*32+quad*8+j
    frag_ab afr[2][4];
    #pragma unroll
    for (int s = 0; s < 2; ++s) {
        const bf16* ap = fn + (size_t)(row_base + s * 16 + l15) * D + quad * 8;
        #pragma unroll
        for (int kb = 0; kb < 4; ++kb) afr[s][kb] = *(const frag_ab*)(ap + kb * 32);
    }
    float li[2][4];
    #pragma unroll
    for (int s = 0; s < 2; ++s)
        #pragma unroll
        for (int r = 0; r < 4; ++r)
            li[s][r] = lab[row_base + s * 16 + quad * 4 + r];

    float se[2][4] = {}, sp[2][4] = {}, cnt[2][4] = {};

    __syncthreads();   // drains DMA vmcnt; colbuf + lab_s ready

    #pragma unroll
    for (int sub = 0; sub < 8; ++sub) {
        const int c = sub * 16 + l15;          // column within tile (c&15 == l15)
        frag_ab b[4];
        #pragma unroll
        for (int kb = 0; kb < 4; ++kb)
            b[kb] = *(const frag_ab*)(&colbuf[(size_t)c * D + (((quad + 4 * kb) ^ l15) * 8)]);
        frag_cd a0 = {0.f, 0.f, 0.f, 0.f}, a1 = {0.f, 0.f, 0.f, 0.f};
        #pragma unroll
        for (int kb = 0; kb < 4; ++kb) {
            a0 = mfma16(afr[0][kb], b[kb], a0);
            a1 = mfma16(afr[1][kb], b[kb], a1);
        }
        const float lj = lab_s[c];
        float cs_e = 0.f, cs_sp = 0.f, cs_cnt = 0.f;
        #pragma unroll
        for (int s = 0; s < 2; ++s) {
            const frag_cd& acc = s ? a1 : a0;
            #pragma unroll
            for (int r = 0; r < 4; ++r) {
                const float sv = acc[r];                      // raw dot (cosine)
                const float e  = __builtin_amdgcn_exp2f(__builtin_fmaf(sv, C1, -C1));
                const float pm = (fabsf(li[s][r] - lj) < THRESH) ? 1.0f : 0.0f;
                se[s][r]  += e;
                sp[s][r]   = __builtin_fmaf(pm, sv, sp[s][r]); // raw dots; 1/T in k3
                cnt[s][r] += pm;
                cs_e  += e;                                    // col-side (symmetric credit)
                cs_sp  = __builtin_fmaf(pm, sv, cs_sp);
                cs_cnt += pm;
            }
        }
        if (!diagblk) {
            // reduce over the 4 quads -> col totals for this wave's 32 rows
            cs_e  += __shfl_xor(cs_e, 16, 64);  cs_e  += __shfl_xor(cs_e, 32, 64);
            cs_sp += __shfl_xor(cs_sp, 16, 64); cs_sp += __shfl_xor(cs_sp, 32, 64);
            cs_cnt+= __shfl_xor(cs_cnt,16, 64); cs_cnt+= __shfl_xor(cs_cnt,32, 64);
            if (lane < 16) {
                csum[wave][0][c] = cs_e;
                csum[wave][1][c] = cs_sp;
                csum[wave][2][c] = cs_cnt;
            }
        }
    }

    // row-side: reduce across the 16 lanes of each quad-group -> split Cb (plain stores)
    #pragma unroll
    for (int s = 0; s < 2; ++s)
        #pragma unroll
        for (int r = 0; r < 4; ++r) {
            #pragma unroll
            for (int m = 1; m < 16; m <<= 1) {
                se[s][r]  += __shfl_xor(se[s][r],  m, 64);
                sp[s][r]  += __shfl_xor(sp[s][r],  m, 64);
                cnt[s][r] += __shfl_xor(cnt[s][r], m, 64);
            }
        }
    if (l15 == 0) {
        #pragma unroll
        for (int s = 0; s < 2; ++s)
            #pragma unroll
            for (int r = 0; r < 4; ++r) {
                const int i = row_base + s * 16 + quad * 4 + r;
                se_p[(size_t)Cb * n + i]  = se[s][r];
                sp_p[(size_t)Cb * n + i]  = sp[s][r];
                cnt_p[(size_t)Cb * n + i] = cnt[s][r];
            }
    }

    // col-side combine -> split Rb (off-diag only; block-uniform branch, barrier safe)
    if (!diagblk) {
        __syncthreads();                       // csum ds_writes visible
        if (tid < TC) {
            const float ve = csum[0][0][tid] + csum[1][0][tid] + csum[2][0][tid] + csum[3][0][tid];
            const float vs = csum[0][1][tid] + csum[1][1][tid] + csum[2][1][tid] + csum[3][1][tid];
            const float vc = csum[0][2][tid] + csum[1][2][tid] + csum[2][2][tid] + csum[3][2][tid];
            se_p[(size_t)Rb * n + col_base + tid]  = ve;
            sp_p[(size_t)Rb * n + col_base + tid]  = vs;
            cnt_p[(size_t)Rb * n + col_base + tid] = vc;
        }
    }
}

// ------- kernel 3: per-row finalize (sum 64 splits) + grid reduction (last-block) -------
__global__ __launch_bounds__(256) void k3_finalize(
    const float* __restrict__ diag, const float* __restrict__ se_p,
    const float* __restrict__ sp_p, const float* __restrict__ cnt_p,
    float* __restrict__ acc, unsigned* __restrict__ counter,
    float* __restrict__ out, int n, int nb)
{
    const int row = blockIdx.x * 256 + threadIdx.x;
    float se = 0.f, sp = 0.f, cnt = 0.f;
    for (int s = 0; s < nb; ++s) {
        se  += se_p[(size_t)s * n + row];
        sp  += sp_p[(size_t)s * n + row];
        cnt += cnt_p[(size_t)s * n + row];
    }
    const float s_ii = diag[row];
    se  -= __builtin_amdgcn_exp2f(__builtin_fmaf(s_ii, C1, -C1));
    sp  -= s_ii;
    cnt -= 1.0f;
    float loss = INVT + __logf(se) - (sp * INVT) / fmaxf(cnt, 1.0f);

    // block reduce
    #pragma unroll
    for (int m = 32; m >= 1; m >>= 1) loss += __shfl_xor(loss, m, 64);
    __shared__ float wsum[4];
    if ((threadIdx.x & 63) == 0) wsum[threadIdx.x >> 6] = loss;
    __syncthreads();
    if (threadIdx.x == 0) {
        const float bs = wsum[0] + wsum[1] + wsum[2] + wsum[3];
        atomicAdd(acc, bs);
        __threadfence();
        const unsigned old = atomicAdd(counter, 1u);
        if (old == gridDim.x - 1) {
            const float total = atomicAdd(acc, 0.0f);  // atomic load, same-address order
            out[0] = total / (float)n;
        }
    }
}

extern "C" void kernel_launch(void* const* d_in, const int* in_sizes, int n_in,
                              void* d_out, int out_size, void* d_ws, size_t ws_size,
                              hipStream_t stream) {
    const float* feat = (const float*)d_in[0];
    const float* lab  = (const float*)d_in[1];
    const int n = in_sizes[1];              // 8192
    const int nb = n / TC;                  // 64 block-rows
    float* out = (float*)d_out;

    // ws: fn (n*D bf16 = 2MB) | diag (n f32) | se_p | sp_p | cnt_p (each nb*n f32 = 2MB)
    //     | acc | counter
    char* ws = (char*)d_ws;
    bf16* fn = (bf16*)ws;
    size_t off = (size_t)n * D * sizeof(bf16);
    float* diag  = (float*)(ws + off); off += (size_t)n * sizeof(float);
    float* se_p  = (float*)(ws + off); off += (size_t)nb * n * sizeof(float);
    float* sp_p  = (float*)(ws + off); off += (size_t)nb * n * sizeof(float);
    float* cnt_p = (float*)(ws + off); off += (size_t)nb * n * sizeof(float);
    float* acc   = (float*)(ws + off); off += sizeof(float);
    unsigned* counter = (unsigned*)(ws + off);

    k1_normalize<<<n / 4, 256, 0, stream>>>(feat, fn, diag, acc, counter, n);
    const int ntri = nb * (nb + 1) / 2;     // 2080 live tiles
    k2_main<<<ntri, 256, 0, stream>>>(fn, lab, se_p, sp_p, cnt_p, n, nb);
    k3_finalize<<<n / 256, 256, 0, stream>>>(diag, se_p, sp_p, cnt_p, acc, counter, out, n, nb);
}